// Round 11
// baseline (286.395 us; speedup 1.0000x reference)
//
#include <hip/hip_runtime.h>

// Problem constants: B=2, C=256, planes=64, T=8, D=H=W=16
// spatial per batch S = T*D*H*W = 32768
#define S_TOT 32768

typedef unsigned short ushortT;
typedef __attribute__((ext_vector_type(8))) short short8;
typedef __attribute__((ext_vector_type(4))) float floatx4;

__device__ __forceinline__ ushortT f2bf(float f) {
    unsigned u = __float_as_uint(f);
    u = (u + 0x7fffu + ((u >> 16) & 1u)) >> 16;
    return (ushortT)u;
}
__device__ __forceinline__ float bf2f(ushortT h) {
    return __uint_as_float(((unsigned)h) << 16);
}
// normalize+relu a dword holding two bf16 of one channel, repack to bf16x2
__device__ __forceinline__ uint32_t nrm2(uint32_t u, float a, float bs) {
    float lo = fmaxf(fmaf(a, bf2f((ushortT)(u & 0xffffu)), bs), 0.f);
    float hi = fmaxf(fmaf(a, bf2f((ushortT)(u >> 16)), bs), 0.f);
    return (uint32_t)f2bf(lo) | ((uint32_t)f2bf(hi) << 16);
}

// Striped stats buffer: 8 stripes x 768 floats.
// Within a stripe: sum1[64] @0, sq1[64] @64, sum2[64] @128, sq2[64] @192,
//                  sum3[256] @256, sq3[256] @512.
#define NSTRIPE 8
#define STRIDE_ST 768

// ---------------------------------------------------------------------------
// Prep weights + zero stats stripes.
__global__ __launch_bounds__(256) void k_prep_w(const float* __restrict__ w1,
                                                const float* __restrict__ w2,
                                                const float* __restrict__ w3,
                                                ushortT* __restrict__ wb1,
                                                ushortT* __restrict__ wb2,
                                                ushortT* __restrict__ wb3,
                                                float* __restrict__ stats) {
    int idx = blockIdx.x * 256 + threadIdx.x;
    if (idx < 16384) {
        int e = idx;
        int j = e & 7, o = (e >> 3) & 63, q = (e >> 9) & 3, cc = e >> 11;
        int c = cc * 32 + q * 8 + j;
        wb1[e] = f2bf(w1[o * 256 + c]);
    } else if (idx < 16384 + 331776) {
        int e = idx - 16384;
        int j = e & 7, o = (e >> 3) & 63, cb = (e >> 9) & 7, tap = e >> 12;
        int c = cb * 8 + j;
        wb2[e] = f2bf(w2[((size_t)o * 64 + c) * 81 + tap]);
    } else if (idx < 16384 + 331776 + 16384) {
        int e = idx - 348160;
        int j = e & 7, o = (e >> 3) & 255, g = e >> 11;
        int ks = g >> 2, q = g & 3;
        int c = ks * 32 + q * 8 + j;
        wb3[e] = f2bf(w3[o * 64 + c]);
    } else if (idx < 364544 + NSTRIPE * STRIDE_ST) {
        stats[idx - 364544] = 0.f;
    }
}

// ---------------------------------------------------------------------------
// Collapse stripes -> per-channel (a, bs) coefficients. 1 block, nch threads.
__global__ __launch_bounds__(256) void k_coef(const float* __restrict__ stats,
                                              int off, int nch,
                                              const float* __restrict__ g,
                                              const float* __restrict__ bb,
                                              float* __restrict__ coef) {
    int c = threadIdx.x;
    if (c >= nch) return;
    float s = 0.f, qv = 0.f;
#pragma unroll
    for (int p = 0; p < NSTRIPE; ++p) {
        s  += stats[p * STRIDE_ST + off + c];
        qv += stats[p * STRIDE_ST + off + nch + c];
    }
    const float inv_n = 1.f / 65536.f;
    float mu = s * inv_n, var = qv * inv_n - mu * mu;
    float a  = g[c] * rsqrtf(var + 1e-5f);
    coef[2 * c]     = a;
    coef[2 * c + 1] = bb[c] - mu * a;
}

// ---------------------------------------------------------------------------
// bn1-apply pass: y1n = bf16(relu(a*y1bf + bs)). Each block spans one channel
// (2048 elems within a 32768-elem channel), so the coef reduction over the 8
// stats stripes is block-uniform scalar work -- the k_coef1 launch is folded
// in here (one fewer kernel).
__global__ __launch_bounds__(256) void k_prep(const ushortT* __restrict__ yin,
                                              const float* __restrict__ stats,
                                              const float* __restrict__ g,
                                              const float* __restrict__ bb,
                                              ushortT* __restrict__ yout) {
    size_t i = ((size_t)blockIdx.x * 256 + threadIdx.x) * 8;
    int c = (int)((i >> 15) & 63);
    float s = 0.f, qv = 0.f;
#pragma unroll
    for (int p = 0; p < NSTRIPE; ++p) {
        s  += stats[p * STRIDE_ST + c];
        qv += stats[p * STRIDE_ST + 64 + c];
    }
    const float inv_n = 1.f / 65536.f;
    float mu = s * inv_n, var = qv * inv_n - mu * mu;
    float a  = g[c] * rsqrtf(var + 1e-5f);
    float bs = bb[c] - mu * a;
    uint4 v = *(const uint4*)(yin + i);
    uint4 r;
    r.x = nrm2(v.x, a, bs);
    r.y = nrm2(v.y, a, bs);
    r.z = nrm2(v.z, a, bs);
    r.w = nrm2(v.w, a, bs);
    *(uint4*)(yout + i) = r;
}

// ---------------------------------------------------------------------------
// K1: conv1x1 256->64 via MFMA. Grid 1024 (n-chunks of 64), single-barrier
// double-buffered staging. Fused stats1 -> striped atomics.
__global__ __launch_bounds__(256) void k_conv1_mfma(const float* __restrict__ x,
                                                    const ushortT* __restrict__ wb1,
                                                    ushortT* __restrict__ y1bf,
                                                    float* __restrict__ stats) {
    __shared__ __align__(16) ushortT xb[2][64 * 40];   // [n][c32] stride 40

    int tid = threadIdx.x;
    int blk = blockIdx.x;
    int b  = blk >> 9;
    int n0 = (blk & 511) * 64;

    int lane = tid & 63;
    int wv   = tid >> 6;
    int m    = lane & 15;
    int q    = lane >> 4;

    int c_loc = tid & 31;     // staging channel within chunk
    int ng    = tid >> 5;     // staging n-group (8 groups of 8)

    const float* xbase = x + ((size_t)(b * 256 + c_loc)) * S_TOT + n0 + ng * 8;
    // channel for chunk cc: + cc*32*S_TOT

    floatx4 acc[4];
#pragma unroll
    for (int i = 0; i < 4; ++i) acc[i] = (floatx4){0.f, 0.f, 0.f, 0.f};

    // prologue: load + commit chunk 0 into buffer 0; load afr for cc=0
    short8 afr = *(const short8*)(wb1 + ((q * 64) + wv * 16 + m) * 8);
    {
        float4 v0 = *(const float4*)(xbase);
        float4 v1 = *(const float4*)(xbase + 4);
        int nb = ng * 8;
        ushortT* xd = xb[0];
        xd[(nb + 0) * 40 + c_loc] = f2bf(v0.x);
        xd[(nb + 1) * 40 + c_loc] = f2bf(v0.y);
        xd[(nb + 2) * 40 + c_loc] = f2bf(v0.z);
        xd[(nb + 3) * 40 + c_loc] = f2bf(v0.w);
        xd[(nb + 4) * 40 + c_loc] = f2bf(v1.x);
        xd[(nb + 5) * 40 + c_loc] = f2bf(v1.y);
        xd[(nb + 6) * 40 + c_loc] = f2bf(v1.z);
        xd[(nb + 7) * 40 + c_loc] = f2bf(v1.w);
    }
    __syncthreads();

    for (int cc = 0; cc < 8; ++cc) {
        // issue next chunk's loads (fly under MFMA phase)
        short8 nafr;
        float4 n0v, n1v;
        if (cc < 7) {
            nafr = *(const short8*)(wb1 + ((((cc + 1) * 4 + q) * 64) + wv * 16 + m) * 8);
            const float* xp = xbase + (size_t)(cc + 1) * 32 * S_TOT;
            n0v = *(const float4*)(xp);
            n1v = *(const float4*)(xp + 4);
        }

        // MFMA on current buffer
        const ushortT* xc = xb[cc & 1];
#pragma unroll
        for (int pt = 0; pt < 4; ++pt) {
            short8 bfr = *(const short8*)(xc + (pt * 16 + m) * 40 + q * 8);
            acc[pt] = __builtin_amdgcn_mfma_f32_16x16x32_bf16(afr, bfr, acc[pt], 0, 0, 0);
        }

        // commit next chunk into the other buffer
        if (cc < 7) {
            int nb = ng * 8;
            ushortT* xd = xb[(cc + 1) & 1];
            xd[(nb + 0) * 40 + c_loc] = f2bf(n0v.x);
            xd[(nb + 1) * 40 + c_loc] = f2bf(n0v.y);
            xd[(nb + 2) * 40 + c_loc] = f2bf(n0v.z);
            xd[(nb + 3) * 40 + c_loc] = f2bf(n0v.w);
            xd[(nb + 4) * 40 + c_loc] = f2bf(n1v.x);
            xd[(nb + 5) * 40 + c_loc] = f2bf(n1v.y);
            xd[(nb + 6) * 40 + c_loc] = f2bf(n1v.z);
            xd[(nb + 7) * 40 + c_loc] = f2bf(n1v.w);
            afr = nafr;
        }
        __syncthreads();
    }

    // store bf16 (unnormalized)
#pragma unroll
    for (int pt = 0; pt < 4; ++pt) {
#pragma unroll
        for (int r = 0; r < 4; ++r) {
            int o = wv * 16 + q * 4 + r;
            y1bf[((size_t)(b * 64 + o)) * S_TOT + n0 + pt * 16 + m] = f2bf(acc[pt][r]);
        }
    }

    // fused stats1: channel o = wv*16+q*4+r, positions vary over (pt, m)
    float ssum[4] = {0.f, 0.f, 0.f, 0.f}, ssq[4] = {0.f, 0.f, 0.f, 0.f};
#pragma unroll
    for (int pt = 0; pt < 4; ++pt)
#pragma unroll
        for (int r = 0; r < 4; ++r) {
            float v = acc[pt][r];
            ssum[r] += v;
            ssq[r]  += v * v;
        }
#pragma unroll
    for (int off = 1; off < 16; off <<= 1)
#pragma unroll
        for (int r = 0; r < 4; ++r) {
            ssum[r] += __shfl_xor(ssum[r], off);
            ssq[r]  += __shfl_xor(ssq[r], off);
        }
    if (m == 0) {
        float* st = stats + (blk & (NSTRIPE - 1)) * STRIDE_ST;
#pragma unroll
        for (int r = 0; r < 4; ++r) {
            int o = wv * 16 + q * 4 + r;
            atomicAdd(st + o, ssum[r]);
            atomicAdd(st + 64 + o, ssq[r]);
        }
    }
}

// ---------------------------------------------------------------------------
// K3: conv 3x3x3x3, 64->64 as bf16 MFMA implicit GEMM.
// Reads PRE-NORMALIZED y1n. Grid 1024 (4-row h quarters).
// Wave repartition vs round 7: each wave owns ONE h-row x ALL 64 output
// channels (ot=4, nt=1). Each B fragment read from LDS now feeds 4 MFMAs
// (was 2) -> 18 ds_read_b128/plane/wave (was 36); MFMA:ds = 4:1. Weight
// stream widens to 8 frags/khw, peak 16 live (64 VGPR) -- still under the
// 128 cap, no spill expected (tripwire: WRITE_SIZE must stay ~8.7MB).
// Staging/barrier structure byte-identical to the verified round-7 kernel.
__global__ __launch_bounds__(256, 2) void k_conv2_mfma(
        const ushortT* __restrict__ y1n,   // [b][c][t][d][h][w] bf16, normalized
        const ushortT* __restrict__ wb2,   // [tap][cb][o][j] bf16
        float* __restrict__ stats,         // add stats2
        ushortT* __restrict__ y2bf) {
    __shared__ __align__(16) ushortT xs[108 * 64];   // 6 rows x 18 ppos x 64c
    __shared__ float st2[128];

    int tid = threadIdx.x;
    int blk = blockIdx.x;
    int b  = blk >> 9;
    int t  = (blk >> 6) & 7;
    int d  = (blk >> 2) & 15;
    int h0 = (blk & 3) * 4;

    int lane = tid & 63;
    int wv   = tid >> 6;   // wave owns h-row h0+wv, all 64 o
    int m    = lane & 15;
    int q    = lane >> 4;
    int wp   = wv;

    int c2      = tid & 31;
    int prbase  = tid >> 5;   // 0..7; rows 0..5 staged

    if (tid < 128) st2[tid] = 0.f;

    // per-wave weight fragment base: (tap,ks,ot) -> wb2 offset
    const ushortT* wfb = wb2 + ((size_t)q * 64 + m) * 8;
    // addr(tap, ks, ot) = wfb + ((tap*8 + ks*4)*64 + ot*16) * 8

    floatx4 acc[4];    // [ot], o = ot*16 + q*4 + r
#pragma unroll
    for (int i = 0; i < 4; ++i) acc[i] = (floatx4){0.f, 0.f, 0.f, 0.f};

    const size_t cstride = 32768;
    uint32_t* xsd = (uint32_t*)xs;

    for (int ktd = 0; ktd < 9; ++ktd) {
        int kt = ktd / 3, kd = ktd - kt * 3;
        int tt = t + kt - 1;
        int dd = d + kd - 1;
        bool pv = (tt >= 0 && tt < 8 && dd >= 0 && dd < 16);
        if (!pv) continue;   // zero contribution: skip staging AND MFMAs

        __syncthreads();   // previous plane's MFMA reads done

        if (prbase < 6) {
            int hin = h0 + prbase - 1;
            uint32_t pack[18];
            if (hin >= 0 && hin < 16) {
                const ushortT* p0 = y1n +
                    (((size_t)(b * 64 + 2 * c2) * 8 + tt) * 16 + dd) * 256 + hin * 16;
                const ushortT* p1 = p0 + cstride;
                uint4 r0 = *(const uint4*)p0;
                uint4 r1 = *(const uint4*)(p0 + 8);
                uint4 s0v = *(const uint4*)p1;
                uint4 s1v = *(const uint4*)(p1 + 8);
                uint32_t ra[8] = {r0.x, r0.y, r0.z, r0.w, r1.x, r1.y, r1.z, r1.w};
                uint32_t sa[8] = {s0v.x, s0v.y, s0v.z, s0v.w, s1v.x, s1v.y, s1v.z, s1v.w};
                pack[0] = 0; pack[17] = 0;
#pragma unroll
                for (int k = 0; k < 8; ++k) {
                    pack[1 + 2 * k] = (ra[k] & 0xffffu) | (sa[k] << 16);
                    pack[2 + 2 * k] = (ra[k] >> 16) | (sa[k] & 0xffff0000u);
                }
            } else {
#pragma unroll
                for (int k = 0; k < 18; ++k) pack[k] = 0;
            }
            int pb = prbase * 18;
#pragma unroll
            for (int k = 0; k < 18; ++k) {
                int ppos = pb + k;
                // dword index within 32-dword row, 16B-chunk swizzled
                xsd[ppos * 32 + ((((c2 >> 2) ^ (ppos & 7)) << 2) | (c2 & 3))] = pack[k];
            }
        }

        // issue khw=0 fragment loads before the barrier (fly during the wait)
        int tap0 = ktd * 9;
        short8 f00 = *(const short8*)(wfb + ((size_t)(tap0 * 8) * 64) * 8);
        short8 f01 = *(const short8*)(wfb + ((size_t)(tap0 * 8) * 64 + 16) * 8);
        short8 f02 = *(const short8*)(wfb + ((size_t)(tap0 * 8) * 64 + 32) * 8);
        short8 f03 = *(const short8*)(wfb + ((size_t)(tap0 * 8) * 64 + 48) * 8);
        short8 f10 = *(const short8*)(wfb + ((size_t)(tap0 * 8 + 4) * 64) * 8);
        short8 f11 = *(const short8*)(wfb + ((size_t)(tap0 * 8 + 4) * 64 + 16) * 8);
        short8 f12 = *(const short8*)(wfb + ((size_t)(tap0 * 8 + 4) * 64 + 32) * 8);
        short8 f13 = *(const short8*)(wfb + ((size_t)(tap0 * 8 + 4) * 64 + 48) * 8);

        __syncthreads();   // LDS ready

#pragma unroll
        for (int khw = 0; khw < 9; ++khw) {
            short8 n00, n01, n02, n03, n10, n11, n12, n13;
            if (khw < 8) {
                int tap = tap0 + khw + 1;
                n00 = *(const short8*)(wfb + ((size_t)(tap * 8) * 64) * 8);
                n01 = *(const short8*)(wfb + ((size_t)(tap * 8) * 64 + 16) * 8);
                n02 = *(const short8*)(wfb + ((size_t)(tap * 8) * 64 + 32) * 8);
                n03 = *(const short8*)(wfb + ((size_t)(tap * 8) * 64 + 48) * 8);
                n10 = *(const short8*)(wfb + ((size_t)(tap * 8 + 4) * 64) * 8);
                n11 = *(const short8*)(wfb + ((size_t)(tap * 8 + 4) * 64 + 16) * 8);
                n12 = *(const short8*)(wfb + ((size_t)(tap * 8 + 4) * 64 + 32) * 8);
                n13 = *(const short8*)(wfb + ((size_t)(tap * 8 + 4) * 64 + 48) * 8);
            }
            int kh = khw / 3, kw = khw - kh * 3;
            int ppos = (wp + kh) * 18 + m + kw;
            int sw = (ppos & 7);
            const ushortT* row = xs + ppos * 64;
            short8 b0  = *(const short8*)(row + ((q ^ sw) << 3));
            short8 b1f = *(const short8*)(row + (((4 + q) ^ sw) << 3));
            acc[0] = __builtin_amdgcn_mfma_f32_16x16x32_bf16(f00, b0, acc[0], 0, 0, 0);
            acc[1] = __builtin_amdgcn_mfma_f32_16x16x32_bf16(f01, b0, acc[1], 0, 0, 0);
            acc[2] = __builtin_amdgcn_mfma_f32_16x16x32_bf16(f02, b0, acc[2], 0, 0, 0);
            acc[3] = __builtin_amdgcn_mfma_f32_16x16x32_bf16(f03, b0, acc[3], 0, 0, 0);
            acc[0] = __builtin_amdgcn_mfma_f32_16x16x32_bf16(f10, b1f, acc[0], 0, 0, 0);
            acc[1] = __builtin_amdgcn_mfma_f32_16x16x32_bf16(f11, b1f, acc[1], 0, 0, 0);
            acc[2] = __builtin_amdgcn_mfma_f32_16x16x32_bf16(f12, b1f, acc[2], 0, 0, 0);
            acc[3] = __builtin_amdgcn_mfma_f32_16x16x32_bf16(f13, b1f, acc[3], 0, 0, 0);
            f00 = n00; f01 = n01; f02 = n02; f03 = n03;
            f10 = n10; f11 = n11; f12 = n12; f13 = n13;
            // bound register liveness / stop load re-hoisting (spill guard)
            asm volatile("" ::: "memory");
        }
    }

    // store bf16: channel o = ot*16 + q*4 + r, row hh = h0 + wp
    {
        int hh = h0 + wp;
        ushortT* yb = y2bf + (((size_t)(b * 64) * 8 + t) * 16 + d) * 256 + hh * 16 + m;
#pragma unroll
        for (int ot = 0; ot < 4; ++ot) {
#pragma unroll
            for (int r = 0; r < 4; ++r) {
                int o = ot * 16 + q * 4 + r;
                yb[(size_t)o * 8 * 16 * 256] = f2bf(acc[ot][r]);
            }
        }
    }

    // fused stats2: all 4 waves cover the same 64 channels -> LDS combine.
    float ss[4], sqv[4];
#pragma unroll
    for (int ot = 0; ot < 4; ++ot) {
        float s = 0.f, qv2 = 0.f;
#pragma unroll
        for (int r = 0; r < 4; ++r) {
            // per-channel partial: must keep r separate; do r-wise below
        }
        (void)s; (void)qv2;
    }
    float s2[4][4], q2[4][4];
#pragma unroll
    for (int ot = 0; ot < 4; ++ot)
#pragma unroll
        for (int r = 0; r < 4; ++r) {
            float v = acc[ot][r];
            s2[ot][r] = v;
            q2[ot][r] = v * v;
        }
#pragma unroll
    for (int off = 1; off < 16; off <<= 1)
#pragma unroll
        for (int ot = 0; ot < 4; ++ot)
#pragma unroll
            for (int r = 0; r < 4; ++r) {
                s2[ot][r] += __shfl_xor(s2[ot][r], off);
                q2[ot][r] += __shfl_xor(q2[ot][r], off);
            }
    if (m == 0) {
#pragma unroll
        for (int ot = 0; ot < 4; ++ot)
#pragma unroll
            for (int r = 0; r < 4; ++r) {
                int o = ot * 16 + q * 4 + r;
                atomicAdd(&st2[o], s2[ot][r]);
                atomicAdd(&st2[64 + o], q2[ot][r]);
            }
    }
    __syncthreads();
    if (tid < 128)
        atomicAdd(stats + (blk & (NSTRIPE - 1)) * STRIDE_ST + 128 + tid, st2[tid]);
}

// ---------------------------------------------------------------------------
// K5: conv1x1 64->256 via MFMA; stages RAW y2bf applying bn2+relu (coef2),
// writes y3 fp32 (d_out). Fused stats3 via striped atomics.
__global__ __launch_bounds__(256) void k_conv3_mfma(const ushortT* __restrict__ y2bf,
                                                    const ushortT* __restrict__ wb3,
                                                    const float* __restrict__ coef2,
                                                    float* __restrict__ stats,
                                                    float* __restrict__ y3) {
    __shared__ __align__(16) ushortT yb[64 * 72];   // [n][c64] stride 72

    int tid = threadIdx.x;
    int blk = blockIdx.x;
    int b  = blk >> 9;
    int n0 = (blk & 511) * 64;

    int lane = tid & 63;
    int wv   = tid >> 6;
    int m    = lane & 15;
    int q    = lane >> 4;

    // stage y2bf: 64 n x 64 c, transposed, bn2+relu inline
    for (int idx = tid; idx < 512; idx += 256) {
        int c = idx >> 3, k = idx & 7;
        float2 cc2 = *(const float2*)(coef2 + 2 * c);
        float a = cc2.x, bs = cc2.y;
        uint4 v = *(const uint4*)(y2bf + ((size_t)(b * 64 + c)) * S_TOT + n0 + k * 8);
        uint32_t va[4] = {v.x, v.y, v.z, v.w};
#pragma unroll
        for (int p = 0; p < 4; ++p) {
            float lo = fmaxf(fmaf(a, bf2f((ushortT)(va[p] & 0xffffu)), bs), 0.f);
            float hi = fmaxf(fmaf(a, bf2f((ushortT)(va[p] >> 16)), bs), 0.f);
            yb[(k * 8 + 2 * p)     * 72 + c] = f2bf(lo);
            yb[(k * 8 + 2 * p + 1) * 72 + c] = f2bf(hi);
        }
    }
    __syncthreads();

    floatx4 acc[4][4];
#pragma unroll
    for (int i = 0; i < 4; ++i)
#pragma unroll
        for (int j = 0; j < 4; ++j) acc[i][j] = (floatx4){0.f, 0.f, 0.f, 0.f};

#pragma unroll
    for (int ks = 0; ks < 2; ++ks) {
        short8 afr[4];
#pragma unroll
        for (int ot = 0; ot < 4; ++ot)
            afr[ot] = *(const short8*)(wb3 +
                (((ks * 4 + q) * 256) + wv * 64 + ot * 16 + m) * 8);
#pragma unroll
        for (int pt = 0; pt < 4; ++pt) {
            short8 bfr = *(const short8*)(yb + (pt * 16 + m) * 72 + ks * 32 + q * 8);
#pragma unroll
            for (int ot = 0; ot < 4; ++ot)
                acc[ot][pt] = __builtin_amdgcn_mfma_f32_16x16x32_bf16(
                    afr[ot], bfr, acc[ot][pt], 0, 0, 0);
        }
    }

    // store fp32
#pragma unroll
    for (int ot = 0; ot < 4; ++ot) {
#pragma unroll
        for (int pt = 0; pt < 4; ++pt) {
#pragma unroll
            for (int r = 0; r < 4; ++r) {
                int o = wv * 64 + ot * 16 + q * 4 + r;
                y3[((size_t)(b * 256 + o)) * S_TOT + n0 + pt * 16 + m] = acc[ot][pt][r];
            }
        }
    }

    // fused stats3: channel o = wv*64+ot*16+q*4+r (waves own disjoint channels)
    float ssum[4][4], ssq[4][4];
#pragma unroll
    for (int ot = 0; ot < 4; ++ot)
#pragma unroll
        for (int r = 0; r < 4; ++r) {
            float s = 0.f, qv = 0.f;
#pragma unroll
            for (int pt = 0; pt < 4; ++pt) {
                float v = acc[ot][pt][r];
                s += v; qv += v * v;
            }
            ssum[ot][r] = s; ssq[ot][r] = qv;
        }
#pragma unroll
    for (int off = 1; off < 16; off <<= 1)
#pragma unroll
        for (int ot = 0; ot < 4; ++ot)
#pragma unroll
            for (int r = 0; r < 4; ++r) {
                ssum[ot][r] += __shfl_xor(ssum[ot][r], off);
                ssq[ot][r]  += __shfl_xor(ssq[ot][r], off);
            }
    if (m == 0) {
        float* st = stats + (blk & (NSTRIPE - 1)) * STRIDE_ST;
#pragma unroll
        for (int ot = 0; ot < 4; ++ot)
#pragma unroll
            for (int r = 0; r < 4; ++r) {
                int o = wv * 64 + ot * 16 + q * 4 + r;
                atomicAdd(st + 256 + o, ssum[ot][r]);
                atomicAdd(st + 512 + o, ssq[ot][r]);
            }
    }
}

// ---------------------------------------------------------------------------
// K7: out = relu(bn3(y3) + x), in place on d_out; stats3 summed from stripes
// with a blockIdx-derived (scalar) channel index.
__global__ __launch_bounds__(256) void k_final(const float* __restrict__ x,
                                               const float* __restrict__ stats,
                                               const float* __restrict__ g,
                                               const float* __restrict__ bb,
                                               float* __restrict__ out) {
    size_t i = ((size_t)blockIdx.x * 256 + threadIdx.x) * 4;
    int o = (int)((blockIdx.x >> 5) & 255);   // scalar: block covers one channel
    float s = 0.f, qv = 0.f;
#pragma unroll
    for (int p = 0; p < NSTRIPE; ++p) {
        s  += stats[p * STRIDE_ST + 256 + o];
        qv += stats[p * STRIDE_ST + 512 + o];
    }
    const float n = 65536.f;
    float mean = s / n;
    float var  = qv / n - mean * mean;
    float a  = g[o] * rsqrtf(var + 1e-5f);
    float bs = bb[o] - mean * a;
    float4 y  = *(float4*)(out + i);
    float4 xv = *(const float4*)(x + i);
    float4 r;
    r.x = fmaxf(a * y.x + bs + xv.x, 0.f);
    r.y = fmaxf(a * y.y + bs + xv.y, 0.f);
    r.z = fmaxf(a * y.z + bs + xv.z, 0.f);
    r.w = fmaxf(a * y.w + bs + xv.w, 0.f);
    *(float4*)(out + i) = r;
}

// ---------------------------------------------------------------------------
extern "C" void kernel_launch(void* const* d_in, const int* in_sizes, int n_in,
                              void* d_out, int out_size, void* d_ws, size_t ws_size,
                              hipStream_t stream) {
    const float* x  = (const float*)d_in[0];
    const float* w1 = (const float*)d_in[1];
    const float* g1 = (const float*)d_in[2];
    const float* b1 = (const float*)d_in[3];
    const float* w2 = (const float*)d_in[4];
    const float* g2 = (const float*)d_in[5];
    const float* b2 = (const float*)d_in[6];
    const float* w3 = (const float*)d_in[7];
    const float* g3 = (const float*)d_in[8];
    const float* b3 = (const float*)d_in[9];

    char* ws = (char*)d_ws;
    ushortT* y1bf = (ushortT*)(ws);                //  8 MiB
    ushortT* y1n  = (ushortT*)(ws + 8388608);      //  8 MiB
    ushortT* y2bf = (ushortT*)(ws + 16777216);     //  8 MiB
    ushortT* wb1  = (ushortT*)(ws + 25165824);     //  32 KiB
    ushortT* wb2  = (ushortT*)(ws + 25198592);     // 648 KiB
    ushortT* wb3  = (ushortT*)(ws + 25862144);     //  32 KiB
    float*   stats = (float*)(ws + 25894912);      // 8*768 floats = 24 KiB
    float*   coef2 = (float*)(ws + 25919488);      // 128 floats
    float* y3 = (float*)d_out;

    // grid covers 364544 weight elems + 6144 stats zeroing = 370688 = 1448*256
    k_prep_w     <<<1448,  256, 0, stream>>>(w1, w2, w3, wb1, wb2, wb3, stats);
    k_conv1_mfma <<<1024,  256, 0, stream>>>(x, wb1, y1bf, stats);
    k_prep       <<<2048,  256, 0, stream>>>(y1bf, stats, g1, b1, y1n);
    k_conv2_mfma <<<1024,  256, 0, stream>>>(y1n, wb2, stats, y2bf);
    k_coef       <<<1,     256, 0, stream>>>(stats, 128, 64, g2, b2, coef2);
    k_conv3_mfma <<<1024,  256, 0, stream>>>(y2bf, wb3, coef2, stats, y3);
    k_final      <<<16384, 256, 0, stream>>>(x, stats, g3, b3, y3);
}

// Round 12
// 252.361 us; speedup vs baseline: 1.1349x; 1.1349x over previous
//
#include <hip/hip_runtime.h>

// Problem constants: B=2, C=256, planes=64, T=8, D=H=W=16
// spatial per batch S = T*D*H*W = 32768
#define S_TOT 32768

typedef unsigned short ushortT;
typedef __attribute__((ext_vector_type(8))) short short8;
typedef __attribute__((ext_vector_type(4))) float floatx4;

__device__ __forceinline__ ushortT f2bf(float f) {
    unsigned u = __float_as_uint(f);
    u = (u + 0x7fffu + ((u >> 16) & 1u)) >> 16;
    return (ushortT)u;
}
__device__ __forceinline__ float bf2f(ushortT h) {
    return __uint_as_float(((unsigned)h) << 16);
}
// normalize+relu a dword holding two bf16 of one channel, repack to bf16x2
__device__ __forceinline__ uint32_t nrm2(uint32_t u, float a, float bs) {
    float lo = fmaxf(fmaf(a, bf2f((ushortT)(u & 0xffffu)), bs), 0.f);
    float hi = fmaxf(fmaf(a, bf2f((ushortT)(u >> 16)), bs), 0.f);
    return (uint32_t)f2bf(lo) | ((uint32_t)f2bf(hi) << 16);
}

// Striped stats buffer: 8 stripes x 768 floats.
// Within a stripe: sum1[64] @0, sq1[64] @64, sum2[64] @128, sq2[64] @192,
//                  sum3[256] @256, sq3[256] @512.
#define NSTRIPE 8
#define STRIDE_ST 768

// ---------------------------------------------------------------------------
// Prep weights + zero stats stripes.
__global__ __launch_bounds__(256) void k_prep_w(const float* __restrict__ w1,
                                                const float* __restrict__ w2,
                                                const float* __restrict__ w3,
                                                ushortT* __restrict__ wb1,
                                                ushortT* __restrict__ wb2,
                                                ushortT* __restrict__ wb3,
                                                float* __restrict__ stats) {
    int idx = blockIdx.x * 256 + threadIdx.x;
    if (idx < 16384) {
        int e = idx;
        int j = e & 7, o = (e >> 3) & 63, q = (e >> 9) & 3, cc = e >> 11;
        int c = cc * 32 + q * 8 + j;
        wb1[e] = f2bf(w1[o * 256 + c]);
    } else if (idx < 16384 + 331776) {
        int e = idx - 16384;
        int j = e & 7, o = (e >> 3) & 63, cb = (e >> 9) & 7, tap = e >> 12;
        int c = cb * 8 + j;
        wb2[e] = f2bf(w2[((size_t)o * 64 + c) * 81 + tap]);
    } else if (idx < 16384 + 331776 + 16384) {
        int e = idx - 348160;
        int j = e & 7, o = (e >> 3) & 255, g = e >> 11;
        int ks = g >> 2, q = g & 3;
        int c = ks * 32 + q * 8 + j;
        wb3[e] = f2bf(w3[o * 64 + c]);
    } else if (idx < 364544 + NSTRIPE * STRIDE_ST) {
        stats[idx - 364544] = 0.f;
    }
}

// ---------------------------------------------------------------------------
// Collapse stripes -> per-channel (a, bs) coefficients. 1 block, nch threads.
__global__ __launch_bounds__(256) void k_coef(const float* __restrict__ stats,
                                              int off, int nch,
                                              const float* __restrict__ g,
                                              const float* __restrict__ bb,
                                              float* __restrict__ coef) {
    int c = threadIdx.x;
    if (c >= nch) return;
    float s = 0.f, qv = 0.f;
#pragma unroll
    for (int p = 0; p < NSTRIPE; ++p) {
        s  += stats[p * STRIDE_ST + off + c];
        qv += stats[p * STRIDE_ST + off + nch + c];
    }
    const float inv_n = 1.f / 65536.f;
    float mu = s * inv_n, var = qv * inv_n - mu * mu;
    float a  = g[c] * rsqrtf(var + 1e-5f);
    coef[2 * c]     = a;
    coef[2 * c + 1] = bb[c] - mu * a;
}

// ---------------------------------------------------------------------------
// bn1-apply pass: y1n = bf16(relu(a*y1bf + bs)). Each block spans one channel,
// so the coef reduction over the 8 stats stripes is block-uniform scalar work
// (k_coef1 folded in).
__global__ __launch_bounds__(256) void k_prep(const ushortT* __restrict__ yin,
                                              const float* __restrict__ stats,
                                              const float* __restrict__ g,
                                              const float* __restrict__ bb,
                                              ushortT* __restrict__ yout) {
    size_t i = ((size_t)blockIdx.x * 256 + threadIdx.x) * 8;
    int c = (int)((i >> 15) & 63);
    float s = 0.f, qv = 0.f;
#pragma unroll
    for (int p = 0; p < NSTRIPE; ++p) {
        s  += stats[p * STRIDE_ST + c];
        qv += stats[p * STRIDE_ST + 64 + c];
    }
    const float inv_n = 1.f / 65536.f;
    float mu = s * inv_n, var = qv * inv_n - mu * mu;
    float a  = g[c] * rsqrtf(var + 1e-5f);
    float bs = bb[c] - mu * a;
    uint4 v = *(const uint4*)(yin + i);
    uint4 r;
    r.x = nrm2(v.x, a, bs);
    r.y = nrm2(v.y, a, bs);
    r.z = nrm2(v.z, a, bs);
    r.w = nrm2(v.w, a, bs);
    *(uint4*)(yout + i) = r;
}

// ---------------------------------------------------------------------------
// K1: conv1x1 256->64 via MFMA. Grid 1024 (n-chunks of 64), single-barrier
// double-buffered staging. Fused stats1 -> striped atomics.
__global__ __launch_bounds__(256) void k_conv1_mfma(const float* __restrict__ x,
                                                    const ushortT* __restrict__ wb1,
                                                    ushortT* __restrict__ y1bf,
                                                    float* __restrict__ stats) {
    __shared__ __align__(16) ushortT xb[2][64 * 40];   // [n][c32] stride 40

    int tid = threadIdx.x;
    int blk = blockIdx.x;
    int b  = blk >> 9;
    int n0 = (blk & 511) * 64;

    int lane = tid & 63;
    int wv   = tid >> 6;
    int m    = lane & 15;
    int q    = lane >> 4;

    int c_loc = tid & 31;     // staging channel within chunk
    int ng    = tid >> 5;     // staging n-group (8 groups of 8)

    const float* xbase = x + ((size_t)(b * 256 + c_loc)) * S_TOT + n0 + ng * 8;
    // channel for chunk cc: + cc*32*S_TOT

    floatx4 acc[4];
#pragma unroll
    for (int i = 0; i < 4; ++i) acc[i] = (floatx4){0.f, 0.f, 0.f, 0.f};

    // prologue: load + commit chunk 0 into buffer 0; load afr for cc=0
    short8 afr = *(const short8*)(wb1 + ((q * 64) + wv * 16 + m) * 8);
    {
        float4 v0 = *(const float4*)(xbase);
        float4 v1 = *(const float4*)(xbase + 4);
        int nb = ng * 8;
        ushortT* xd = xb[0];
        xd[(nb + 0) * 40 + c_loc] = f2bf(v0.x);
        xd[(nb + 1) * 40 + c_loc] = f2bf(v0.y);
        xd[(nb + 2) * 40 + c_loc] = f2bf(v0.z);
        xd[(nb + 3) * 40 + c_loc] = f2bf(v0.w);
        xd[(nb + 4) * 40 + c_loc] = f2bf(v1.x);
        xd[(nb + 5) * 40 + c_loc] = f2bf(v1.y);
        xd[(nb + 6) * 40 + c_loc] = f2bf(v1.z);
        xd[(nb + 7) * 40 + c_loc] = f2bf(v1.w);
    }
    __syncthreads();

    for (int cc = 0; cc < 8; ++cc) {
        // issue next chunk's loads (fly under MFMA phase)
        short8 nafr;
        float4 n0v, n1v;
        if (cc < 7) {
            nafr = *(const short8*)(wb1 + ((((cc + 1) * 4 + q) * 64) + wv * 16 + m) * 8);
            const float* xp = xbase + (size_t)(cc + 1) * 32 * S_TOT;
            n0v = *(const float4*)(xp);
            n1v = *(const float4*)(xp + 4);
        }

        // MFMA on current buffer
        const ushortT* xc = xb[cc & 1];
#pragma unroll
        for (int pt = 0; pt < 4; ++pt) {
            short8 bfr = *(const short8*)(xc + (pt * 16 + m) * 40 + q * 8);
            acc[pt] = __builtin_amdgcn_mfma_f32_16x16x32_bf16(afr, bfr, acc[pt], 0, 0, 0);
        }

        // commit next chunk into the other buffer
        if (cc < 7) {
            int nb = ng * 8;
            ushortT* xd = xb[(cc + 1) & 1];
            xd[(nb + 0) * 40 + c_loc] = f2bf(n0v.x);
            xd[(nb + 1) * 40 + c_loc] = f2bf(n0v.y);
            xd[(nb + 2) * 40 + c_loc] = f2bf(n0v.z);
            xd[(nb + 3) * 40 + c_loc] = f2bf(n0v.w);
            xd[(nb + 4) * 40 + c_loc] = f2bf(n1v.x);
            xd[(nb + 5) * 40 + c_loc] = f2bf(n1v.y);
            xd[(nb + 6) * 40 + c_loc] = f2bf(n1v.z);
            xd[(nb + 7) * 40 + c_loc] = f2bf(n1v.w);
            afr = nafr;
        }
        __syncthreads();
    }

    // store bf16 (unnormalized)
#pragma unroll
    for (int pt = 0; pt < 4; ++pt) {
#pragma unroll
        for (int r = 0; r < 4; ++r) {
            int o = wv * 16 + q * 4 + r;
            y1bf[((size_t)(b * 64 + o)) * S_TOT + n0 + pt * 16 + m] = f2bf(acc[pt][r]);
        }
    }

    // fused stats1: channel o = wv*16+q*4+r, positions vary over (pt, m)
    float ssum[4] = {0.f, 0.f, 0.f, 0.f}, ssq[4] = {0.f, 0.f, 0.f, 0.f};
#pragma unroll
    for (int pt = 0; pt < 4; ++pt)
#pragma unroll
        for (int r = 0; r < 4; ++r) {
            float v = acc[pt][r];
            ssum[r] += v;
            ssq[r]  += v * v;
        }
#pragma unroll
    for (int off = 1; off < 16; off <<= 1)
#pragma unroll
        for (int r = 0; r < 4; ++r) {
            ssum[r] += __shfl_xor(ssum[r], off);
            ssq[r]  += __shfl_xor(ssq[r], off);
        }
    if (m == 0) {
        float* st = stats + (blk & (NSTRIPE - 1)) * STRIDE_ST;
#pragma unroll
        for (int r = 0; r < 4; ++r) {
            int o = wv * 16 + q * 4 + r;
            atomicAdd(st + o, ssum[r]);
            atomicAdd(st + 64 + o, ssq[r]);
        }
    }
}

// ---------------------------------------------------------------------------
// K3: conv 3x3x3x3, 64->64 as bf16 MFMA implicit GEMM.
// Reads PRE-NORMALIZED y1n. Grid 512 (8-row h halves, h0=(blk&1)*8).
// Wave = (wp h-quad) x (wo och-half): nt=4 h-rows, ot=2, ks=2. Each weight
// fragment feeds FOUR MFMAs (was 2 in the 68us version, so weight L2 traffic
// halves to ~0.52GB; the ot=4 variant quadrupled it to 2.1GB and regressed).
// Each act B-fragment feeds 2 MFMAs (LDS ratio 8 reads : 16 MFMAs per khw).
// 1-deep weight streaming (4+4 frags = 32 VGPR live). Staging identical to
// the verified round-1 geometry: rows 0..9 staged by pr in {prbase,prbase+8}.
// Fused stats2 via LDS + striped atomics.
__global__ __launch_bounds__(256, 2) void k_conv2_mfma(
        const ushortT* __restrict__ y1n,   // [b][c][t][d][h][w] bf16, normalized
        const ushortT* __restrict__ wb2,   // [tap][cb][o][j] bf16
        float* __restrict__ stats,         // add stats2
        ushortT* __restrict__ y2bf) {
    __shared__ __align__(16) ushortT xs[180 * 64];   // 10 rows x 18 wpos x 64c
    __shared__ float st2[128];

    int tid = threadIdx.x;
    int blk = blockIdx.x;
    int b  = blk >> 8;
    int t  = (blk >> 5) & 7;
    int d  = (blk >> 1) & 15;
    int h0 = (blk & 1) * 8;

    int lane = tid & 63;
    int wv   = tid >> 6;
    int m    = lane & 15;
    int q    = lane >> 4;
    int wp   = wv & 1;     // h-quad: rows wp*4 .. wp*4+3 within the 8
    int wo   = wv >> 1;    // o half: o in [wo*32, wo*32+32)

    int c2      = tid & 31;
    int prbase  = tid >> 5;   // rows pr in {prbase, prbase+8}, pr<10

    if (tid < 128) st2[tid] = 0.f;

    // per-wave weight fragment base: (tap,ks,ot) -> wb2 offset
    const ushortT* wfb = wb2 + ((size_t)q * 64 + wo * 32 + m) * 8;
    // addr(tap, ks, ot) = wfb + ((tap*8 + ks*4)*64 + ot*16) * 8

    floatx4 acc[2][4];     // [ot][nt]
#pragma unroll
    for (int i = 0; i < 2; ++i)
#pragma unroll
        for (int j = 0; j < 4; ++j) acc[i][j] = (floatx4){0.f, 0.f, 0.f, 0.f};

    const size_t cstride = 32768;
    uint32_t* xsd = (uint32_t*)xs;

    for (int ktd = 0; ktd < 9; ++ktd) {
        int kt = ktd / 3, kd = ktd - kt * 3;
        int tt = t + kt - 1;
        int dd = d + kd - 1;
        bool pv = (tt >= 0 && tt < 8 && dd >= 0 && dd < 16);
        if (!pv) continue;   // zero contribution: skip staging AND MFMAs

        __syncthreads();   // previous plane's MFMA reads done

        for (int pr = prbase; pr < 10; pr += 8) {
            int hin = h0 + pr - 1;
            uint32_t pack[18];
            if (hin >= 0 && hin < 16) {
                const ushortT* p0 = y1n +
                    (((size_t)(b * 64 + 2 * c2) * 8 + tt) * 16 + dd) * 256 + hin * 16;
                const ushortT* p1 = p0 + cstride;
                uint4 r0 = *(const uint4*)p0;
                uint4 r1 = *(const uint4*)(p0 + 8);
                uint4 s0v = *(const uint4*)p1;
                uint4 s1v = *(const uint4*)(p1 + 8);
                uint32_t ra[8] = {r0.x, r0.y, r0.z, r0.w, r1.x, r1.y, r1.z, r1.w};
                uint32_t sa[8] = {s0v.x, s0v.y, s0v.z, s0v.w, s1v.x, s1v.y, s1v.z, s1v.w};
                pack[0] = 0; pack[17] = 0;
#pragma unroll
                for (int k = 0; k < 8; ++k) {
                    pack[1 + 2 * k] = (ra[k] & 0xffffu) | (sa[k] << 16);
                    pack[2 + 2 * k] = (ra[k] >> 16) | (sa[k] & 0xffff0000u);
                }
            } else {
#pragma unroll
                for (int k = 0; k < 18; ++k) pack[k] = 0;
            }
            int pb = pr * 18;
#pragma unroll
            for (int k = 0; k < 18; ++k) {
                int ppos = pb + k;
                // dword index within 32-dword row, 16B-chunk swizzled
                xsd[ppos * 32 + ((((c2 >> 2) ^ (ppos & 7)) << 2) | (c2 & 3))] = pack[k];
            }
        }

        // issue khw=0 fragment loads before the barrier (fly during the wait)
        int tap0 = ktd * 9;
        short8 c00 = *(const short8*)(wfb + ((size_t)(tap0 * 8) * 64) * 8);
        short8 c01 = *(const short8*)(wfb + ((size_t)(tap0 * 8) * 64 + 16) * 8);
        short8 c10 = *(const short8*)(wfb + ((size_t)(tap0 * 8 + 4) * 64) * 8);
        short8 c11 = *(const short8*)(wfb + ((size_t)(tap0 * 8 + 4) * 64 + 16) * 8);

        __syncthreads();   // LDS ready

#pragma unroll
        for (int khw = 0; khw < 9; ++khw) {
            short8 n00, n01, n10, n11;
            if (khw < 8) {
                int tap = tap0 + khw + 1;
                n00 = *(const short8*)(wfb + ((size_t)(tap * 8) * 64) * 8);
                n01 = *(const short8*)(wfb + ((size_t)(tap * 8) * 64 + 16) * 8);
                n10 = *(const short8*)(wfb + ((size_t)(tap * 8 + 4) * 64) * 8);
                n11 = *(const short8*)(wfb + ((size_t)(tap * 8 + 4) * 64 + 16) * 8);
            }
            int kh = khw / 3, kw = khw - kh * 3;
#pragma unroll
            for (int nt = 0; nt < 4; ++nt) {
                int ppos = (wp * 4 + nt + kh) * 18 + m + kw;
                int sw = (ppos & 7);
                const ushortT* row = xs + ppos * 64;
                short8 b0  = *(const short8*)(row + ((q ^ sw) << 3));
                short8 b1f = *(const short8*)(row + (((4 + q) ^ sw) << 3));
                acc[0][nt] = __builtin_amdgcn_mfma_f32_16x16x32_bf16(
                    c00, b0, acc[0][nt], 0, 0, 0);
                acc[1][nt] = __builtin_amdgcn_mfma_f32_16x16x32_bf16(
                    c01, b0, acc[1][nt], 0, 0, 0);
                acc[0][nt] = __builtin_amdgcn_mfma_f32_16x16x32_bf16(
                    c10, b1f, acc[0][nt], 0, 0, 0);
                acc[1][nt] = __builtin_amdgcn_mfma_f32_16x16x32_bf16(
                    c11, b1f, acc[1][nt], 0, 0, 0);
            }
            c00 = n00; c01 = n01; c10 = n10; c11 = n11;
            // bound register liveness / stop load re-hoisting (spill guard)
            asm volatile("" ::: "memory");
        }
    }

    // store bf16: channel o = wo*32 + ot*16 + q*4 + r, row hh = h0 + wp*4 + nt
#pragma unroll
    for (int ot = 0; ot < 2; ++ot) {
#pragma unroll
        for (int nt = 0; nt < 4; ++nt) {
#pragma unroll
            for (int r = 0; r < 4; ++r) {
                int o  = wo * 32 + ot * 16 + q * 4 + r;
                int hh = h0 + wp * 4 + nt;
                y2bf[(((size_t)(b * 64 + o) * 8 + t) * 16 + d) * 256 + hh * 16 + m] =
                    f2bf(acc[ot][nt][r]);
            }
        }
    }

    // fused stats2: wp-waves share channels -> LDS combine, then stripe.
    float ss[2][4], sqv[2][4];
#pragma unroll
    for (int ot = 0; ot < 2; ++ot)
#pragma unroll
        for (int r = 0; r < 4; ++r) {
            float s = 0.f, qv = 0.f;
#pragma unroll
            for (int nt = 0; nt < 4; ++nt) {
                float v = acc[ot][nt][r];
                s += v; qv += v * v;
            }
            ss[ot][r] = s; sqv[ot][r] = qv;
        }
#pragma unroll
    for (int off = 1; off < 16; off <<= 1)
#pragma unroll
        for (int ot = 0; ot < 2; ++ot)
#pragma unroll
            for (int r = 0; r < 4; ++r) {
                ss[ot][r]  += __shfl_xor(ss[ot][r], off);
                sqv[ot][r] += __shfl_xor(sqv[ot][r], off);
            }
    if (m == 0) {
#pragma unroll
        for (int ot = 0; ot < 2; ++ot)
#pragma unroll
            for (int r = 0; r < 4; ++r) {
                int o = wo * 32 + ot * 16 + q * 4 + r;
                atomicAdd(&st2[o], ss[ot][r]);
                atomicAdd(&st2[64 + o], sqv[ot][r]);
            }
    }
    __syncthreads();
    if (tid < 128)
        atomicAdd(stats + (blk & (NSTRIPE - 1)) * STRIDE_ST + 128 + tid, st2[tid]);
}

// ---------------------------------------------------------------------------
// K5: conv1x1 64->256 via MFMA; stages RAW y2bf applying bn2+relu (coef2),
// writes y3 fp32 (d_out). Fused stats3 via striped atomics.
__global__ __launch_bounds__(256) void k_conv3_mfma(const ushortT* __restrict__ y2bf,
                                                    const ushortT* __restrict__ wb3,
                                                    const float* __restrict__ coef2,
                                                    float* __restrict__ stats,
                                                    float* __restrict__ y3) {
    __shared__ __align__(16) ushortT yb[64 * 72];   // [n][c64] stride 72

    int tid = threadIdx.x;
    int blk = blockIdx.x;
    int b  = blk >> 9;
    int n0 = (blk & 511) * 64;

    int lane = tid & 63;
    int wv   = tid >> 6;
    int m    = lane & 15;
    int q    = lane >> 4;

    // stage y2bf: 64 n x 64 c, transposed, bn2+relu inline
    for (int idx = tid; idx < 512; idx += 256) {
        int c = idx >> 3, k = idx & 7;
        float2 cc2 = *(const float2*)(coef2 + 2 * c);
        float a = cc2.x, bs = cc2.y;
        uint4 v = *(const uint4*)(y2bf + ((size_t)(b * 64 + c)) * S_TOT + n0 + k * 8);
        uint32_t va[4] = {v.x, v.y, v.z, v.w};
#pragma unroll
        for (int p = 0; p < 4; ++p) {
            float lo = fmaxf(fmaf(a, bf2f((ushortT)(va[p] & 0xffffu)), bs), 0.f);
            float hi = fmaxf(fmaf(a, bf2f((ushortT)(va[p] >> 16)), bs), 0.f);
            yb[(k * 8 + 2 * p)     * 72 + c] = f2bf(lo);
            yb[(k * 8 + 2 * p + 1) * 72 + c] = f2bf(hi);
        }
    }
    __syncthreads();

    floatx4 acc[4][4];
#pragma unroll
    for (int i = 0; i < 4; ++i)
#pragma unroll
        for (int j = 0; j < 4; ++j) acc[i][j] = (floatx4){0.f, 0.f, 0.f, 0.f};

#pragma unroll
    for (int ks = 0; ks < 2; ++ks) {
        short8 afr[4];
#pragma unroll
        for (int ot = 0; ot < 4; ++ot)
            afr[ot] = *(const short8*)(wb3 +
                (((ks * 4 + q) * 256) + wv * 64 + ot * 16 + m) * 8);
#pragma unroll
        for (int pt = 0; pt < 4; ++pt) {
            short8 bfr = *(const short8*)(yb + (pt * 16 + m) * 72 + ks * 32 + q * 8);
#pragma unroll
            for (int ot = 0; ot < 4; ++ot)
                acc[ot][pt] = __builtin_amdgcn_mfma_f32_16x16x32_bf16(
                    afr[ot], bfr, acc[ot][pt], 0, 0, 0);
        }
    }

    // store fp32
#pragma unroll
    for (int ot = 0; ot < 4; ++ot) {
#pragma unroll
        for (int pt = 0; pt < 4; ++pt) {
#pragma unroll
            for (int r = 0; r < 4; ++r) {
                int o = wv * 64 + ot * 16 + q * 4 + r;
                y3[((size_t)(b * 256 + o)) * S_TOT + n0 + pt * 16 + m] = acc[ot][pt][r];
            }
        }
    }

    // fused stats3: channel o = wv*64+ot*16+q*4+r (waves own disjoint channels)
    float ssum[4][4], ssq[4][4];
#pragma unroll
    for (int ot = 0; ot < 4; ++ot)
#pragma unroll
        for (int r = 0; r < 4; ++r) {
            float s = 0.f, qv = 0.f;
#pragma unroll
            for (int pt = 0; pt < 4; ++pt) {
                float v = acc[ot][pt][r];
                s += v; qv += v * v;
            }
            ssum[ot][r] = s; ssq[ot][r] = qv;
        }
#pragma unroll
    for (int off = 1; off < 16; off <<= 1)
#pragma unroll
        for (int ot = 0; ot < 4; ++ot)
#pragma unroll
            for (int r = 0; r < 4; ++r) {
                ssum[ot][r] += __shfl_xor(ssum[ot][r], off);
                ssq[ot][r]  += __shfl_xor(ssq[ot][r], off);
            }
    if (m == 0) {
        float* st = stats + (blk & (NSTRIPE - 1)) * STRIDE_ST;
#pragma unroll
        for (int ot = 0; ot < 4; ++ot)
#pragma unroll
            for (int r = 0; r < 4; ++r) {
                int o = wv * 64 + ot * 16 + q * 4 + r;
                atomicAdd(st + 256 + o, ssum[ot][r]);
                atomicAdd(st + 512 + o, ssq[ot][r]);
            }
    }
}

// ---------------------------------------------------------------------------
// K7: out = relu(bn3(y3) + x), in place on d_out; stats3 summed from stripes
// with a blockIdx-derived (scalar) channel index.
__global__ __launch_bounds__(256) void k_final(const float* __restrict__ x,
                                               const float* __restrict__ stats,
                                               const float* __restrict__ g,
                                               const float* __restrict__ bb,
                                               float* __restrict__ out) {
    size_t i = ((size_t)blockIdx.x * 256 + threadIdx.x) * 4;
    int o = (int)((blockIdx.x >> 5) & 255);   // scalar: block covers one channel
    float s = 0.f, qv = 0.f;
#pragma unroll
    for (int p = 0; p < NSTRIPE; ++p) {
        s  += stats[p * STRIDE_ST + 256 + o];
        qv += stats[p * STRIDE_ST + 512 + o];
    }
    const float n = 65536.f;
    float mean = s / n;
    float var  = qv / n - mean * mean;
    float a  = g[o] * rsqrtf(var + 1e-5f);
    float bs = bb[o] - mean * a;
    float4 y  = *(float4*)(out + i);
    float4 xv = *(const float4*)(x + i);
    float4 r;
    r.x = fmaxf(a * y.x + bs + xv.x, 0.f);
    r.y = fmaxf(a * y.y + bs + xv.y, 0.f);
    r.z = fmaxf(a * y.z + bs + xv.z, 0.f);
    r.w = fmaxf(a * y.w + bs + xv.w, 0.f);
    *(float4*)(out + i) = r;
}

// ---------------------------------------------------------------------------
extern "C" void kernel_launch(void* const* d_in, const int* in_sizes, int n_in,
                              void* d_out, int out_size, void* d_ws, size_t ws_size,
                              hipStream_t stream) {
    const float* x  = (const float*)d_in[0];
    const float* w1 = (const float*)d_in[1];
    const float* g1 = (const float*)d_in[2];
    const float* b1 = (const float*)d_in[3];
    const float* w2 = (const float*)d_in[4];
    const float* g2 = (const float*)d_in[5];
    const float* b2 = (const float*)d_in[6];
    const float* w3 = (const float*)d_in[7];
    const float* g3 = (const float*)d_in[8];
    const float* b3 = (const float*)d_in[9];

    char* ws = (char*)d_ws;
    ushortT* y1bf = (ushortT*)(ws);                //  8 MiB
    ushortT* y1n  = (ushortT*)(ws + 8388608);      //  8 MiB
    ushortT* y2bf = (ushortT*)(ws + 16777216);     //  8 MiB
    ushortT* wb1  = (ushortT*)(ws + 25165824);     //  32 KiB
    ushortT* wb2  = (ushortT*)(ws + 25198592);     // 648 KiB
    ushortT* wb3  = (ushortT*)(ws + 25862144);     //  32 KiB
    float*   stats = (float*)(ws + 25894912);      // 8*768 floats = 24 KiB
    float*   coef2 = (float*)(ws + 25919488);      // 128 floats
    float* y3 = (float*)d_out;

    // grid covers 364544 weight elems + 6144 stats zeroing = 370688 = 1448*256
    k_prep_w     <<<1448,  256, 0, stream>>>(w1, w2, w3, wb1, wb2, wb3, stats);
    k_conv1_mfma <<<1024,  256, 0, stream>>>(x, wb1, y1bf, stats);
    k_prep       <<<2048,  256, 0, stream>>>(y1bf, stats, g1, b1, y1n);
    k_conv2_mfma <<<512,   256, 0, stream>>>(y1n, wb2, stats, y2bf);
    k_coef       <<<1,     256, 0, stream>>>(stats, 128, 64, g2, b2, coef2);
    k_conv3_mfma <<<1024,  256, 0, stream>>>(y2bf, wb3, coef2, stats, y3);
    k_final      <<<16384, 256, 0, stream>>>(x, stats, g3, b3, y3);
}